// Round 5
// baseline (289.264 us; speedup 1.0000x reference)
//
#include <hip/hip_runtime.h>
#include <stdint.h>

#define P_DIM 256
#define NREF  4096
#define NIN   8192
#define DF    512
#define NE    4
#define CREF  1536              // per-element slot capacity (ref rows)   [mean 1024, +18 sigma]
#define CIN   2560              // per-element slot capacity (query rows) [mean 2048, +13 sigma]
#define AE_LD (NE * CREF)       // Ae row stride = 6144

typedef __bf16 bf16x8 __attribute__((ext_vector_type(8)));
typedef float  f32x4  __attribute__((ext_vector_type(4)));
typedef unsigned short ush8 __attribute__((ext_vector_type(8)));

static __device__ __forceinline__ unsigned short f2bf(float f) {
    uint32_t u = __builtin_bit_cast(uint32_t, f);
    u += 0x7FFFu + ((u >> 16) & 1u);
    return (unsigned short)(u >> 16);
}

// Zero the gather destinations (pad rows must be 0) and the 8 bin cursors.
__global__ void prep(unsigned short* __restrict__ Xe, unsigned short* __restrict__ De,
                     int* __restrict__ cnt) {
    const size_t nXe4 = (size_t)NE * CREF * DF / 8;   // uint4 units
    const size_t nDe4 = (size_t)NE * CIN * DF / 8;
    const size_t total = nXe4 + nDe4;
    uint4 z = {0u, 0u, 0u, 0u};
    size_t stride = (size_t)gridDim.x * blockDim.x;
    for (size_t i = blockIdx.x * (size_t)blockDim.x + threadIdx.x; i < total; i += stride) {
        if (i < nXe4) ((uint4*)Xe)[i] = z;
        else          ((uint4*)De)[i - nXe4] = z;
    }
    if (blockIdx.x == 0 && threadIdx.x < 2 * NE) cnt[threadIdx.x] = 0;
}

// One wave per source row: atomic slot in its element bin, cast fp32->bf16,
// write row (1 KB coalesced) + perm entry. Waves [0,NREF) = X_ref, rest = desc.
__global__ void gather_rows(const float* __restrict__ X_ref, const float* __restrict__ desc,
                            const int* __restrict__ Zr, const int* __restrict__ Z,
                            unsigned short* __restrict__ Xe, unsigned short* __restrict__ De,
                            int* __restrict__ iperm, int* __restrict__ jperm,
                            int* __restrict__ cnt) {
    int w = (blockIdx.x * blockDim.x + threadIdx.x) >> 6;
    int lane = threadIdx.x & 63;
    const float* src;
    unsigned short* dstp;
    if (w < NREF) {
        int i = w, e = Zr[i], s = 0;
        if (lane == 0) s = atomicAdd(&cnt[e], 1);
        s = __shfl(s, 0);
        int dst = e * CREF + s;
        if (lane == 0) iperm[dst] = i;
        src = X_ref + (size_t)i * DF;
        dstp = Xe + (size_t)dst * DF;
    } else {
        int j = w - NREF, e = Z[j], s = 0;
        if (lane == 0) s = atomicAdd(&cnt[NE + e], 1);
        s = __shfl(s, 0);
        int dst = e * CIN + s;
        if (lane == 0) jperm[dst] = j;
        src = desc + (size_t)j * DF;
        dstp = De + (size_t)dst * DF;
    }
    float4 a = *(const float4*)(src + lane * 8);
    float4 b = *(const float4*)(src + lane * 8 + 4);
    ush8 o;
    o[0] = f2bf(a.x); o[1] = f2bf(a.y); o[2] = f2bf(a.z); o[3] = f2bf(a.w);
    o[4] = f2bf(b.x); o[5] = f2bf(b.y); o[6] = f2bf(b.z); o[7] = f2bf(b.w);
    *(ush8*)(dstp + lane * 8) = o;
}

// Ae[p][e*CREF + ic] = bf16(Alpha[p][iperm[...]]); pad slots -> 0.
// Lane-consecutive = column-consecutive: coalesced writes, gathered L2 reads.
__global__ void alpha_gather(const float* __restrict__ Alpha, const int* __restrict__ iperm,
                             const int* __restrict__ cnt, unsigned short* __restrict__ Ae) {
    int idx = blockIdx.x * blockDim.x + threadIdx.x;   // 0 .. P_DIM*AE_LD
    int p = idx / AE_LD;
    int col = idx - p * AE_LD;
    int e = col / CREF;
    int ic = col - e * CREF;
    unsigned short v = 0;
    if (ic < cnt[e]) v = f2bf(Alpha[(size_t)p * NREF + iperm[col]]);
    Ae[idx] = v;
}

// Per-element GEMM1: Kt_e[jl, il] = (De_jl . Xe_il)^2  (bf16, row stride CREF).
// 128x128 tile, BK=64, 4 waves, global_load_lds w=16, XOR chunk swizzle.
__global__ __launch_bounds__(256) void g1_grouped(
    const unsigned short* __restrict__ DeA, const unsigned short* __restrict__ XeA,
    unsigned short* __restrict__ KtA, const int* __restrict__ cnt) {
    constexpr int BK = 64;
    const int e = blockIdx.z;
    const int cntR = cnt[e], cntI = cnt[NE + e];
    const int padR = (cntR + 127) & ~127;
    const int padI = (cntI + 127) & ~127;
    const int m0 = blockIdx.y * 128;   // jl (query rows)
    const int n0 = blockIdx.x * 128;   // il (ref rows)
    if (m0 >= padI || n0 >= padR) return;

    const unsigned short* A = DeA + (size_t)e * CIN * DF;
    const unsigned short* B = XeA + (size_t)e * CREF * DF;
    unsigned short* C = KtA + (size_t)e * CIN * CREF;

    __shared__ unsigned short tA[128 * BK];
    __shared__ unsigned short tB[128 * BK];

    const int tid = threadIdx.x, wave = tid >> 6, lane = tid & 63;
    const int wr = wave >> 1, wc = wave & 1;
    const int waveM = wr * 64, waveN = wc * 64;
    const int lrow = lane >> 3, ls = lane & 7;
    const int l15 = lane & 15, lq = lane >> 4;

    f32x4 acc[4][4];
#pragma unroll
    for (int r = 0; r < 4; ++r)
#pragma unroll
        for (int c = 0; c < 4; ++c) acc[r][c] = (f32x4){0.f, 0.f, 0.f, 0.f};

#pragma unroll 1
    for (int k0 = 0; k0 < DF; k0 += BK) {
        __syncthreads();
#pragma unroll
        for (int it = 0; it < 8; ++it) {           // 32 chunks / 4 waves
            int cb = wave + it * 4;
            bool isB = cb >= 16;
            int cb2 = isB ? cb - 16 : cb;
            int row = cb2 * 8 + lrow;
            int g = ls ^ (row & 7);
            const unsigned short* gp = (isB ? B : A)
                + (size_t)((isB ? n0 : m0) + row) * DF + (size_t)(k0 + g * 8);
            unsigned short* lp = (isB ? tB : tA) + cb2 * (8 * BK);
            __builtin_amdgcn_global_load_lds(
                (const __attribute__((address_space(1))) void*)gp,
                (__attribute__((address_space(3))) void*)lp, 16, 0, 0);
        }
        __syncthreads();
#pragma unroll
        for (int kk = 0; kk < BK; kk += 32) {
            const int cbase = kk >> 3;
            bf16x8 af[4], bf[4];
#pragma unroll
            for (int r = 0; r < 4; ++r) {
                int m = waveM + r * 16 + l15;
                int ch = (cbase + lq) ^ (m & 7);
                af[r] = *(const bf16x8*)&tA[m * BK + ch * 8];
            }
#pragma unroll
            for (int c = 0; c < 4; ++c) {
                int n = waveN + c * 16 + l15;
                int ch = (cbase + lq) ^ (n & 7);
                bf[c] = *(const bf16x8*)&tB[n * BK + ch * 8];
            }
#pragma unroll
            for (int r = 0; r < 4; ++r)
#pragma unroll
                for (int c = 0; c < 4; ++c)
                    acc[r][c] = __builtin_amdgcn_mfma_f32_16x16x32_bf16(
                        af[r], bf[c], acc[r][c], 0, 0, 0);
        }
    }

    // C/D layout: col = lane&15, row = (lane>>4)*4 + reg
#pragma unroll
    for (int r = 0; r < 4; ++r) {
        int mb = m0 + waveM + r * 16 + lq * 4;
#pragma unroll
        for (int reg = 0; reg < 4; ++reg) {
            size_t ro = (size_t)(mb + reg) * CREF;
#pragma unroll
            for (int c = 0; c < 4; ++c) {
                int n = n0 + waveN + c * 16 + l15;
                float v = acc[r][c][reg];
                C[ro + n] = f2bf(v * v);
            }
        }
    }
}

// Per-element GEMM2 + scatter: out[p, jperm[jl]] = sum_il Ae[p,il] * Kt_e[jl,il].
// BM=128 (p) x BN=64 (jl), dynamic K = padR, fp32 acc, scatter epilogue.
__global__ __launch_bounds__(256) void g2_grouped(
    const unsigned short* __restrict__ Ae, const unsigned short* __restrict__ KtA,
    const int* __restrict__ jperm, const int* __restrict__ cnt,
    float* __restrict__ out) {
    constexpr int BK = 64;
    const int e = blockIdx.z;
    const int cntR = cnt[e], cntI = cnt[NE + e];
    const int padR = (cntR + 127) & ~127;
    const int n0 = blockIdx.x * 64;    // jl
    const int m0 = blockIdx.y * 128;   // p
    if (n0 >= cntI) return;

    const unsigned short* B = KtA + (size_t)e * CIN * CREF;  // rows jl, stride CREF

    __shared__ unsigned short tA[128 * BK];
    __shared__ unsigned short tB[64 * BK];

    const int tid = threadIdx.x, wave = tid >> 6, lane = tid & 63;
    const int wr = wave >> 1, wc = wave & 1;
    const int waveM = wr * 64, waveN = wc * 32;   // RT=4 (p), CT=2 (jl)
    const int lrow = lane >> 3, ls = lane & 7;
    const int l15 = lane & 15, lq = lane >> 4;

    f32x4 acc[4][2];
#pragma unroll
    for (int r = 0; r < 4; ++r)
#pragma unroll
        for (int c = 0; c < 2; ++c) acc[r][c] = (f32x4){0.f, 0.f, 0.f, 0.f};

#pragma unroll 1
    for (int k0 = 0; k0 < padR; k0 += BK) {
        __syncthreads();
#pragma unroll
        for (int it = 0; it < 6; ++it) {           // (128+64)/8 = 24 chunks / 4 waves
            int cb = wave + it * 4;
            bool isB = cb >= 16;
            int cb2 = isB ? cb - 16 : cb;
            int row = cb2 * 8 + lrow;
            int g = ls ^ (row & 7);
            const unsigned short* gp = isB
                ? B + (size_t)(n0 + row) * CREF + (size_t)(k0 + g * 8)
                : Ae + (size_t)(m0 + row) * AE_LD + (size_t)(e * CREF + k0 + g * 8);
            unsigned short* lp = (isB ? tB : tA) + cb2 * (8 * BK);
            __builtin_amdgcn_global_load_lds(
                (const __attribute__((address_space(1))) void*)gp,
                (__attribute__((address_space(3))) void*)lp, 16, 0, 0);
        }
        __syncthreads();
#pragma unroll
        for (int kk = 0; kk < BK; kk += 32) {
            const int cbase = kk >> 3;
            bf16x8 af[4], bf[2];
#pragma unroll
            for (int r = 0; r < 4; ++r) {
                int m = waveM + r * 16 + l15;
                int ch = (cbase + lq) ^ (m & 7);
                af[r] = *(const bf16x8*)&tA[m * BK + ch * 8];
            }
#pragma unroll
            for (int c = 0; c < 2; ++c) {
                int n = waveN + c * 16 + l15;
                int ch = (cbase + lq) ^ (n & 7);
                bf[c] = *(const bf16x8*)&tB[n * BK + ch * 8];
            }
#pragma unroll
            for (int r = 0; r < 4; ++r)
#pragma unroll
                for (int c = 0; c < 2; ++c)
                    acc[r][c] = __builtin_amdgcn_mfma_f32_16x16x32_bf16(
                        af[r], bf[c], acc[r][c], 0, 0, 0);
        }
    }

    // scatter epilogue: column jl -> out column jperm[e*CIN + jl], guard jl < cntI
    int jok[2], jdest[2];
#pragma unroll
    for (int c = 0; c < 2; ++c) {
        int jl = n0 + waveN + c * 16 + l15;
        jok[c] = jl < cntI;
        jdest[c] = jok[c] ? jperm[e * CIN + jl] : 0;
    }
#pragma unroll
    for (int r = 0; r < 4; ++r) {
        int pb = m0 + waveM + r * 16 + lq * 4;
#pragma unroll
        for (int reg = 0; reg < 4; ++reg) {
            size_t ro = (size_t)(pb + reg) * NIN;
#pragma unroll
            for (int c = 0; c < 2; ++c)
                if (jok[c]) out[ro + jdest[c]] = acc[r][c][reg];
        }
    }
}

extern "C" void kernel_launch(void* const* d_in, const int* in_sizes, int n_in,
                              void* d_out, int out_size, void* d_ws, size_t ws_size,
                              hipStream_t stream) {
    const float* Alpha = (const float*)d_in[0];   // [256, 4096]
    const float* X_ref = (const float*)d_in[1];   // [4096, 512]
    const float* desc  = (const float*)d_in[2];   // [8192, 512]
    const int*   Z_ref = (const int*)d_in[3];     // [4096]
    const int*   Z     = (const int*)d_in[4];     // [8192]
    float* out = (float*)d_out;                   // [256, 8192]

    // ws (ushort units): Xe 6.3MB | De 10.5MB | Ae 3.1MB | Kt 31.5MB | perms/cnt
    unsigned short* Xe = (unsigned short*)d_ws;            // NE*CREF*DF
    unsigned short* De = Xe + (size_t)NE * CREF * DF;      // NE*CIN*DF
    unsigned short* Ae = De + (size_t)NE * CIN * DF;       // P_DIM*AE_LD
    unsigned short* Kt = Ae + (size_t)P_DIM * AE_LD;       // NE*CIN*CREF
    int* iperm = (int*)(Kt + (size_t)NE * CIN * CREF);     // NE*CREF
    int* jperm = iperm + NE * CREF;                        // NE*CIN
    int* cnt   = jperm + NE * CIN;                         // 8

    prep<<<1024, 256, 0, stream>>>(Xe, De, cnt);

    // 12288 rows, one wave each
    gather_rows<<<(NREF + NIN) * 64 / 256, 256, 0, stream>>>(
        X_ref, desc, Z_ref, Z, Xe, De, iperm, jperm, cnt);

    alpha_gather<<<P_DIM * AE_LD / 256, 256, 0, stream>>>(Alpha, iperm, cnt, Ae);

    g1_grouped<<<dim3(CREF / 128, CIN / 128, NE), 256, 0, stream>>>(De, Xe, Kt, cnt);

    g2_grouped<<<dim3(CIN / 64, P_DIM / 128, NE), 256, 0, stream>>>(Ae, Kt, jperm, cnt, out);
}

// Round 6
// 150.908 us; speedup vs baseline: 1.9168x; 1.9168x over previous
//
#include <hip/hip_runtime.h>
#include <stdint.h>

#define P_DIM 256
#define NREF  4096
#define NIN   8192
#define DF    512
#define NE    4
#define CREF  1536              // per-element capacity (ref rows)   [mean 1024]
#define CIN   2560              // per-element capacity (query rows) [mean 2048]
#define AE_LD (NE * CREF)       // Ae row stride = 6144

typedef __bf16 bf16x8 __attribute__((ext_vector_type(8)));
typedef float  f32x4  __attribute__((ext_vector_type(4)));
typedef unsigned short ush8 __attribute__((ext_vector_type(8)));

static __device__ __forceinline__ unsigned short f2bf(float f) {
    uint32_t u = __builtin_bit_cast(uint32_t, f);
    u += 0x7FFFu + ((u >> 16) & 1u);
    return (unsigned short)(u >> 16);
}

// Single-block stable counting sort: builds iperm (slot->src row for X_ref),
// jperm (slot->src row for desc), cnt[8]. No global atomics.
__global__ __launch_bounds__(256) void plan_sort(
    const int* __restrict__ Zr, const int* __restrict__ Z,
    int* __restrict__ iperm, int* __restrict__ jperm, int* __restrict__ cnt) {
    __shared__ int histX[NE][256];
    __shared__ int histD[NE][256];
    const int t = threadIdx.x;
    constexpr int CHX = NREF / 256;   // 16
    constexpr int CHD = NIN / 256;    // 32

    int lc[NE];
#pragma unroll
    for (int e = 0; e < NE; ++e) lc[e] = 0;
    for (int k = 0; k < CHX; ++k) lc[Zr[t * CHX + k] & (NE - 1)]++;
#pragma unroll
    for (int e = 0; e < NE; ++e) histX[e][t] = lc[e];

#pragma unroll
    for (int e = 0; e < NE; ++e) lc[e] = 0;
    for (int k = 0; k < CHD; ++k) lc[Z[t * CHD + k] & (NE - 1)]++;
#pragma unroll
    for (int e = 0; e < NE; ++e) histD[e][t] = lc[e];

    __syncthreads();
    if (t < 2 * NE) {                  // 8 parallel serial exclusive scans
        int b = t & (NE - 1);
        int isD = t >> 2;
        int run = 0;
        if (!isD) {
            for (int u = 0; u < 256; ++u) { int v = histX[b][u]; histX[b][u] = run; run += v; }
            cnt[b] = run;
        } else {
            for (int u = 0; u < 256; ++u) { int v = histD[b][u]; histD[b][u] = run; run += v; }
            cnt[NE + b] = run;
        }
    }
    __syncthreads();

    int off[NE];
#pragma unroll
    for (int e = 0; e < NE; ++e) off[e] = histX[e][t];
    for (int k = 0; k < CHX; ++k) {
        int i = t * CHX + k;
        int e = Zr[i] & (NE - 1);
        iperm[e * CREF + off[e]++] = i;
    }
#pragma unroll
    for (int e = 0; e < NE; ++e) off[e] = histD[e][t];
    for (int k = 0; k < CHD; ++k) {
        int j = t * CHD + k;
        int e = Z[j] & (NE - 1);
        jperm[e * CIN + off[e]++] = j;
    }
}

// Slot-driven gather: one wave per DESTINATION slot. slot < cnt -> copy+cast
// source row (2KB fp32 read, 1KB bf16 write); else write zeros (pad).
// Absorbs the old prep-zeroing kernel. No atomics.
__global__ void gather_pad(const float* __restrict__ X_ref, const float* __restrict__ desc,
                           const int* __restrict__ iperm, const int* __restrict__ jperm,
                           const int* __restrict__ cnt,
                           unsigned short* __restrict__ Xe, unsigned short* __restrict__ De) {
    int w = (blockIdx.x * blockDim.x + threadIdx.x) >> 6;
    int lane = threadIdx.x & 63;
    const float* src = nullptr;
    unsigned short* dstp;
    if (w < NE * CREF) {
        int e = w / CREF, s = w - e * CREF;
        if (s < cnt[e]) src = X_ref + (size_t)iperm[w] * DF;
        dstp = Xe + (size_t)w * DF;
    } else {
        int w2 = w - NE * CREF;
        int e = w2 / CIN, s = w2 - e * CIN;
        if (s < cnt[NE + e]) src = desc + (size_t)jperm[w2] * DF;
        dstp = De + (size_t)w2 * DF;
    }
    ush8 o;
    if (src) {
        float4 a = *(const float4*)(src + lane * 8);
        float4 b = *(const float4*)(src + lane * 8 + 4);
        o[0] = f2bf(a.x); o[1] = f2bf(a.y); o[2] = f2bf(a.z); o[3] = f2bf(a.w);
        o[4] = f2bf(b.x); o[5] = f2bf(b.y); o[6] = f2bf(b.z); o[7] = f2bf(b.w);
    } else {
        o = (ush8){0, 0, 0, 0, 0, 0, 0, 0};
    }
    *(ush8*)(dstp + lane * 8) = o;
}

// Ae[p][e*CREF + ic] = bf16(Alpha[p][iperm[...]]); pad slots -> 0.
__global__ void alpha_gather(const float* __restrict__ Alpha, const int* __restrict__ iperm,
                             const int* __restrict__ cnt, unsigned short* __restrict__ Ae) {
    int idx = blockIdx.x * blockDim.x + threadIdx.x;
    int p = idx / AE_LD;
    int col = idx - p * AE_LD;
    int e = col / CREF;
    int ic = col - e * CREF;
    unsigned short v = 0;
    if (ic < cnt[e]) v = f2bf(Alpha[(size_t)p * NREF + iperm[col]]);
    Ae[idx] = v;
}

// Per-element GEMM1: Kt_e[jl, il] = (De_jl . Xe_il)^2  (bf16, row stride CREF).
__global__ __launch_bounds__(256) void g1_grouped(
    const unsigned short* __restrict__ DeA, const unsigned short* __restrict__ XeA,
    unsigned short* __restrict__ KtA, const int* __restrict__ cnt) {
    constexpr int BK = 64;
    const int e = blockIdx.z;
    const int padR = (cnt[e] + 127) & ~127;
    const int padI = (cnt[NE + e] + 127) & ~127;
    const int m0 = blockIdx.y * 128;   // jl (query rows)
    const int n0 = blockIdx.x * 128;   // il (ref rows)
    if (m0 >= padI || n0 >= padR) return;

    const unsigned short* A = DeA + (size_t)e * CIN * DF;
    const unsigned short* B = XeA + (size_t)e * CREF * DF;
    unsigned short* C = KtA + (size_t)e * CIN * CREF;

    __shared__ unsigned short tA[128 * BK];
    __shared__ unsigned short tB[128 * BK];

    const int tid = threadIdx.x, wave = tid >> 6, lane = tid & 63;
    const int wr = wave >> 1, wc = wave & 1;
    const int waveM = wr * 64, waveN = wc * 64;
    const int lrow = lane >> 3, ls = lane & 7;
    const int l15 = lane & 15, lq = lane >> 4;

    f32x4 acc[4][4];
#pragma unroll
    for (int r = 0; r < 4; ++r)
#pragma unroll
        for (int c = 0; c < 4; ++c) acc[r][c] = (f32x4){0.f, 0.f, 0.f, 0.f};

#pragma unroll 1
    for (int k0 = 0; k0 < DF; k0 += BK) {
        __syncthreads();
#pragma unroll
        for (int it = 0; it < 8; ++it) {
            int cb = wave + it * 4;
            bool isB = cb >= 16;
            int cb2 = isB ? cb - 16 : cb;
            int row = cb2 * 8 + lrow;
            int g = ls ^ (row & 7);
            const unsigned short* gp = (isB ? B : A)
                + (size_t)((isB ? n0 : m0) + row) * DF + (size_t)(k0 + g * 8);
            unsigned short* lp = (isB ? tB : tA) + cb2 * (8 * BK);
            __builtin_amdgcn_global_load_lds(
                (const __attribute__((address_space(1))) void*)gp,
                (__attribute__((address_space(3))) void*)lp, 16, 0, 0);
        }
        __syncthreads();
#pragma unroll
        for (int kk = 0; kk < BK; kk += 32) {
            const int cbase = kk >> 3;
            bf16x8 af[4], bf[4];
#pragma unroll
            for (int r = 0; r < 4; ++r) {
                int m = waveM + r * 16 + l15;
                int ch = (cbase + lq) ^ (m & 7);
                af[r] = *(const bf16x8*)&tA[m * BK + ch * 8];
            }
#pragma unroll
            for (int c = 0; c < 4; ++c) {
                int n = waveN + c * 16 + l15;
                int ch = (cbase + lq) ^ (n & 7);
                bf[c] = *(const bf16x8*)&tB[n * BK + ch * 8];
            }
#pragma unroll
            for (int r = 0; r < 4; ++r)
#pragma unroll
                for (int c = 0; c < 4; ++c)
                    acc[r][c] = __builtin_amdgcn_mfma_f32_16x16x32_bf16(
                        af[r], bf[c], acc[r][c], 0, 0, 0);
        }
    }

#pragma unroll
    for (int r = 0; r < 4; ++r) {
        int mb = m0 + waveM + r * 16 + lq * 4;
#pragma unroll
        for (int reg = 0; reg < 4; ++reg) {
            size_t ro = (size_t)(mb + reg) * CREF;
#pragma unroll
            for (int c = 0; c < 4; ++c) {
                int n = n0 + waveN + c * 16 + l15;
                float v = acc[r][c][reg];
                C[ro + n] = f2bf(v * v);
            }
        }
    }
}

// Per-element GEMM2 + scatter: out[p, jperm[jl]] = sum_il Ae[p,il] * Kt_e[jl,il].
__global__ __launch_bounds__(256) void g2_grouped(
    const unsigned short* __restrict__ Ae, const unsigned short* __restrict__ KtA,
    const int* __restrict__ jperm, const int* __restrict__ cnt,
    float* __restrict__ out) {
    constexpr int BK = 64;
    const int e = blockIdx.z;
    const int cntI = cnt[NE + e];
    const int padR = (cnt[e] + 127) & ~127;
    const int n0 = blockIdx.x * 64;    // jl
    const int m0 = blockIdx.y * 128;   // p
    if (n0 >= cntI) return;

    const unsigned short* B = KtA + (size_t)e * CIN * CREF;

    __shared__ unsigned short tA[128 * BK];
    __shared__ unsigned short tB[64 * BK];

    const int tid = threadIdx.x, wave = tid >> 6, lane = tid & 63;
    const int wr = wave >> 1, wc = wave & 1;
    const int waveM = wr * 64, waveN = wc * 32;
    const int lrow = lane >> 3, ls = lane & 7;
    const int l15 = lane & 15, lq = lane >> 4;

    f32x4 acc[4][2];
#pragma unroll
    for (int r = 0; r < 4; ++r)
#pragma unroll
        for (int c = 0; c < 2; ++c) acc[r][c] = (f32x4){0.f, 0.f, 0.f, 0.f};

#pragma unroll 1
    for (int k0 = 0; k0 < padR; k0 += BK) {
        __syncthreads();
#pragma unroll
        for (int it = 0; it < 6; ++it) {
            int cb = wave + it * 4;
            bool isB = cb >= 16;
            int cb2 = isB ? cb - 16 : cb;
            int row = cb2 * 8 + lrow;
            int g = ls ^ (row & 7);
            const unsigned short* gp = isB
                ? B + (size_t)(n0 + row) * CREF + (size_t)(k0 + g * 8)
                : Ae + (size_t)(m0 + row) * AE_LD + (size_t)(e * CREF + k0 + g * 8);
            unsigned short* lp = (isB ? tB : tA) + cb2 * (8 * BK);
            __builtin_amdgcn_global_load_lds(
                (const __attribute__((address_space(1))) void*)gp,
                (__attribute__((address_space(3))) void*)lp, 16, 0, 0);
        }
        __syncthreads();
#pragma unroll
        for (int kk = 0; kk < BK; kk += 32) {
            const int cbase = kk >> 3;
            bf16x8 af[4], bf[2];
#pragma unroll
            for (int r = 0; r < 4; ++r) {
                int m = waveM + r * 16 + l15;
                int ch = (cbase + lq) ^ (m & 7);
                af[r] = *(const bf16x8*)&tA[m * BK + ch * 8];
            }
#pragma unroll
            for (int c = 0; c < 2; ++c) {
                int n = waveN + c * 16 + l15;
                int ch = (cbase + lq) ^ (n & 7);
                bf[c] = *(const bf16x8*)&tB[n * BK + ch * 8];
            }
#pragma unroll
            for (int r = 0; r < 4; ++r)
#pragma unroll
                for (int c = 0; c < 2; ++c)
                    acc[r][c] = __builtin_amdgcn_mfma_f32_16x16x32_bf16(
                        af[r], bf[c], acc[r][c], 0, 0, 0);
        }
    }

    int jok[2], jdest[2];
#pragma unroll
    for (int c = 0; c < 2; ++c) {
        int jl = n0 + waveN + c * 16 + l15;
        jok[c] = jl < cntI;
        jdest[c] = jok[c] ? jperm[e * CIN + jl] : 0;
    }
#pragma unroll
    for (int r = 0; r < 4; ++r) {
        int pb = m0 + waveM + r * 16 + lq * 4;
#pragma unroll
        for (int reg = 0; reg < 4; ++reg) {
            size_t ro = (size_t)(pb + reg) * NIN;
#pragma unroll
            for (int c = 0; c < 2; ++c)
                if (jok[c]) out[ro + jdest[c]] = acc[r][c][reg];
        }
    }
}

extern "C" void kernel_launch(void* const* d_in, const int* in_sizes, int n_in,
                              void* d_out, int out_size, void* d_ws, size_t ws_size,
                              hipStream_t stream) {
    const float* Alpha = (const float*)d_in[0];   // [256, 4096]
    const float* X_ref = (const float*)d_in[1];   // [4096, 512]
    const float* desc  = (const float*)d_in[2];   // [8192, 512]
    const int*   Z_ref = (const int*)d_in[3];     // [4096]
    const int*   Z     = (const int*)d_in[4];     // [8192]
    float* out = (float*)d_out;                   // [256, 8192]

    // ws (ushort units): Xe 6.3MB | De 10.5MB | Ae 3.1MB | Kt 31.5MB | perms/cnt
    unsigned short* Xe = (unsigned short*)d_ws;            // NE*CREF*DF
    unsigned short* De = Xe + (size_t)NE * CREF * DF;      // NE*CIN*DF
    unsigned short* Ae = De + (size_t)NE * CIN * DF;       // P_DIM*AE_LD
    unsigned short* Kt = Ae + (size_t)P_DIM * AE_LD;       // NE*CIN*CREF
    int* iperm = (int*)(Kt + (size_t)NE * CIN * CREF);     // NE*CREF
    int* jperm = iperm + NE * CREF;                        // NE*CIN
    int* cnt   = jperm + NE * CIN;                         // 8

    plan_sort<<<1, 256, 0, stream>>>(Z_ref, Z, iperm, jperm, cnt);

    // one wave per destination slot: NE*(CREF+CIN) = 16384 waves
    gather_pad<<<NE * (CREF + CIN) * 64 / 256, 256, 0, stream>>>(
        X_ref, desc, iperm, jperm, cnt, Xe, De);

    alpha_gather<<<P_DIM * AE_LD / 256, 256, 0, stream>>>(Alpha, iperm, cnt, Ae);

    g1_grouped<<<dim3(CREF / 128, CIN / 128, NE), 256, 0, stream>>>(De, Xe, Kt, cnt);

    g2_grouped<<<dim3(CIN / 64, P_DIM / 128, NE), 256, 0, stream>>>(Ae, Kt, jperm, cnt, out);
}